// Round 5
// baseline (593.283 us; speedup 1.0000x reference)
//
#include <hip/hip_runtime.h>
#include <hip/hip_bf16.h>

// B=2, N=512. row = b*512 + i, rows 0..1023.
// R7 = DECOMPOSITION PROBE. Real pipeline byte-identical to R5 (137.1 µs).
// R6 found marginal cost per EdgeConv launch = 11.6 µs but cannot split
// {launch gap, cold-miss, warm in-kernel}. This round:
//   - k2_probe: k2 body looped 16x to scratch -> appears in rocprof top-5;
//     dur/16 = warm in-kernel time, counters show the warm regime's bound.
//   - 4x k_empty (same grid shape) -> total-dur delta gives pure launch gap.
//
// EdgeConv factorization: e@W1 = x_i@(W1_top - W1_bot) + x_j@W1_bot
//   u_i = x_i@(W1_top-W1_bot)+b1 ; v_j = x_j@W1_bot ; h1 = relu(u_i+v_j)
// Masked max over neighbors only (A>0) is exact: h2 = relu(..) >= 0 > -1e9.

#define NEGV -1e9f
#define MAXNBR 96

// Per-wave edge-max partial over edges [beg, beg+myc) of this row.
// Barrier-free: hbuf producer == consumer wave (DS ops in-order per wave), so
// the v-prefetch global loads stay in flight across groups.
__device__ __forceinline__ float edge_partial(
    int beg, int myc, int o, const int* nbr, const float* __restrict__ vb,
    float ui, float bo, const float* wcol, float* hbuf) {
  float acc = NEGV;
  if (myc <= 0) return acc;
  float vl[4];
#pragma unroll
  for (int t = 0; t < 4; t++) {
    int e = t < myc ? t : myc - 1;
    vl[t] = vb[nbr[beg + e] * 64 + o];
  }
  for (int e0 = 0; e0 < myc; e0 += 4) {
    float4 hw;
    hw.x = fmaxf(ui + vl[0], 0.f);
    hw.y = fmaxf(ui + vl[1], 0.f);
    hw.z = fmaxf(ui + vl[2], 0.f);
    hw.w = fmaxf(ui + vl[3], 0.f);
    *(float4*)(hbuf + o * 4) = hw;
    if (e0 + 4 < myc) {
#pragma unroll
      for (int t = 0; t < 4; t++) {
        int e = e0 + 4 + t;
        if (e >= myc) e = myc - 1;
        vl[t] = vb[nbr[beg + e] * 64 + o];  // prefetch next group
      }
    }
    float s0 = bo, s1 = bo, s2 = bo, s3 = bo;
#pragma unroll
    for (int k = 0; k < 64; k++) {
      float4 hv = *(const float4*)(hbuf + k * 4);  // broadcast read
      s0 = fmaf(hv.x, wcol[k], s0);
      s1 = fmaf(hv.y, wcol[k], s1);
      s2 = fmaf(hv.z, wcol[k], s2);
      s3 = fmaf(hv.w, wcol[k], s3);
    }
    acc = fmaxf(acc, fmaxf(s0, 0.f));
    if (e0 + 1 < myc) acc = fmaxf(acc, fmaxf(s1, 0.f));
    if (e0 + 2 < myc) acc = fmaxf(acc, fmaxf(s2, 0.f));
    if (e0 + 3 < myc) acc = fmaxf(acc, fmaxf(s3, 0.f));
  }
  return acc;
}

// K1: nbr-list build (wave1) + node MLP 3->64->64 (wave0) + 4-way u1/v1 GEMV.
__global__ __launch_bounds__(256) void k1_node_uv(
    const float* __restrict__ coords, const float* __restrict__ A,
    const float* __restrict__ nf, const float* __restrict__ cs,
    const float* __restrict__ Wh1, const float* __restrict__ bh1,
    const float* __restrict__ Wh2, const float* __restrict__ bh2,
    const float* __restrict__ W1, const float* __restrict__ b1,
    float* __restrict__ u, float* __restrict__ v,
    int* __restrict__ nbrCnt, int* __restrict__ nbrG) {
  int node = blockIdx.x;
  int tid = threadIdx.x;
  int w = tid >> 6, o = tid & 63;
  __shared__ float t[64];
  __shared__ float xs[128];
  __shared__ float pp[4][64];
  if (w == 1) {
    // Adjacency scan: two float4 loads cover the 512-wide row.
    const float* Arow = A + (size_t)node * 512;
    float4 a0 = *(const float4*)(Arow + o * 4);
    float4 a1 = *(const float4*)(Arow + 256 + o * 4);
    float av[8] = {a0.x, a0.y, a0.z, a0.w, a1.x, a1.y, a1.z, a1.w};
    int base = 0;
#pragma unroll
    for (int j = 0; j < 8; j++) {
      bool p = av[j] > 0.f;
      unsigned long long m = __ballot(p);
      if (p) {
        int pos = base + __builtin_popcountll(m & ((1ull << o) - 1ull));
        int col = (j < 4) ? (4 * o + j) : (256 + 4 * o + (j - 4));
        if (pos < MAXNBR) nbrG[node * MAXNBR + pos] = col;  // order-free (max)
      }
      base += __builtin_popcountll(m);
    }
    if (o == 0) nbrCnt[node] = base < MAXNBR ? base : MAXNBR;
  } else if (w == 0) {
    float c0 = coords[node * 3 + 0];
    float c1 = coords[node * 3 + 1];
    float c2 = coords[node * 3 + 2];
    float a = bh1[o];
    a = fmaf(c0, Wh1[o], a);
    a = fmaf(c1, Wh1[64 + o], a);
    a = fmaf(c2, Wh1[128 + o], a);
    t[o] = fmaxf(a, 0.f);  // same-wave producer/consumer: no barrier needed
    float a2 = bh2[o];
#pragma unroll
    for (int k = 0; k < 64; k++) a2 = fmaf(t[k], Wh2[k * 64 + o], a2);
    xs[o] = fmaxf(a2, 0.f);
    if (o < 63) xs[64 + o] = nf[node * 63 + o];
    if (o == 63) xs[127] = cs[node];
  }
  __syncthreads();
  // 4-way GEMV: w0/w1 = un k-halves of 128; w2/w3 = vn k-halves.
  {
    const float* WbG = W1 + 128 * 64;
    int kb = (w & 1) * 64;
    float a = (w == 0) ? b1[o] : 0.f;
    if (w < 2) {
#pragma unroll
      for (int k = 0; k < 64; k++) {
        int kk = kb + k;
        a = fmaf(xs[kk], W1[kk * 64 + o] - WbG[kk * 64 + o], a);
      }
    } else {
#pragma unroll
      for (int k = 0; k < 64; k++) {
        int kk = kb + k;
        a = fmaf(xs[kk], WbG[kk * 64 + o], a);
      }
    }
    pp[w][o] = a;
  }
  __syncthreads();
  if (w == 0) u[node * 64 + o] = pp[0][o] + pp[1][o];
  else if (w == 1) v[node * 64 + o] = pp[2][o] + pp[3][o];
}

// K2/K3: EdgeConv (+opt residual); writes raw out and u/v for next layer.
// Block = 256 threads (4 waves), one row per block, edges split 4-way,
// tail GEMVs split 4-way.
__global__ __launch_bounds__(256) void k_edgeconv_uv(
    const int* __restrict__ nbrCnt, const int* __restrict__ nbrG,
    const float* __restrict__ u, const float* __restrict__ v,
    const float* __restrict__ W2, const float* __restrict__ b2,
    const float* __restrict__ res,  // may be null
    float* __restrict__ raw_out,
    const float* __restrict__ W1n, const float* __restrict__ b1n,
    float* __restrict__ un, float* __restrict__ vn) {
  __shared__ int s_nbr[MAXNBR];
  __shared__ float s_h[4][64 * 4];
  __shared__ float s_pm[4][64];
  __shared__ float s_xs[64];
  int row = blockIdx.x;
  int tid = threadIdx.x;
  int w = tid >> 6, o = tid & 63;
  int cnt = __builtin_amdgcn_readfirstlane(nbrCnt[row]);
  if (tid < MAXNBR) s_nbr[tid] = (tid < cnt) ? nbrG[row * MAXNBR + tid] : 0;
  float rv = (w == 0 && res) ? res[row * 64 + o] : 0.f;  // early, off-path
  float wcol[64];
#pragma unroll
  for (int k = 0; k < 64; k++) wcol[k] = W2[k * 64 + o];
  float ui = u[row * 64 + o];
  float bo = b2[o];
  const float* vb = v + (size_t)(row >> 9) * (512 * 64);
  __syncthreads();
  int q = (cnt + 3) >> 2;
  int beg = w * q;
  if (beg > cnt) beg = cnt;
  int end = beg + q;
  if (end > cnt) end = cnt;
  s_pm[w][o] = edge_partial(beg, end - beg, o, s_nbr, vb, ui, bo, wcol, s_h[w]);
  __syncthreads();
  if (w == 0) {
    float acc = fmaxf(fmaxf(s_pm[0][o], s_pm[1][o]),
                      fmaxf(s_pm[2][o], s_pm[3][o]));
    raw_out[row * 64 + o] = acc;
    s_xs[o] = acc + rv;
  }
  __syncthreads();
  // 4-way tail GEMV: w0/w1 = un k-halves of 64; w2/w3 = vn k-halves.
  {
    const float* Wb = W1n + 64 * 64;
    int kb = (w & 1) * 32;
    float a = (w == 0) ? b1n[o] : 0.f;
    if (w < 2) {
#pragma unroll
      for (int k = 0; k < 32; k++) {
        int kk = kb + k;
        a = fmaf(s_xs[kk], W1n[kk * 64 + o] - Wb[kk * 64 + o], a);
      }
    } else {
#pragma unroll
      for (int k = 0; k < 32; k++) {
        int kk = kb + k;
        a = fmaf(s_xs[kk], Wb[kk * 64 + o], a);
      }
    }
    s_pm[w][o] = a;  // reuse: edge partials consumed above (barrier-separated)
  }
  __syncthreads();
  if (w == 0) un[row * 64 + o] = s_pm[0][o] + s_pm[1][o];
  else if (w == 1) vn[row * 64 + o] = s_pm[2][o] + s_pm[3][o];
}

// PROBE: k2 body looped `reps` times to scratch. dur/reps = warm in-kernel t.
__global__ __launch_bounds__(256) void k2_probe(
    const int* __restrict__ nbrCnt, const int* __restrict__ nbrG,
    const float* __restrict__ u, const float* __restrict__ v,
    const float* __restrict__ W2, const float* __restrict__ b2,
    float* __restrict__ raw_out,
    const float* __restrict__ W1n, const float* __restrict__ b1n,
    float* __restrict__ un, float* __restrict__ vn, int reps) {
  __shared__ int s_nbr[MAXNBR];
  __shared__ float s_h[4][64 * 4];
  __shared__ float s_pm[4][64];
  __shared__ float s_xs[64];
  int row = blockIdx.x;
  int tid = threadIdx.x;
  int w = tid >> 6, o = tid & 63;
  int cnt = __builtin_amdgcn_readfirstlane(nbrCnt[row]);
  if (tid < MAXNBR) s_nbr[tid] = (tid < cnt) ? nbrG[row * MAXNBR + tid] : 0;
  float wcol[64];
#pragma unroll
  for (int k = 0; k < 64; k++) wcol[k] = W2[k * 64 + o];
  float ui = u[row * 64 + o];
  float bo = b2[o];
  const float* vb = v + (size_t)(row >> 9) * (512 * 64);
  __syncthreads();
  int q = (cnt + 3) >> 2;
  int beg = w * q;
  if (beg > cnt) beg = cnt;
  int end = beg + q;
  if (end > cnt) end = cnt;
  for (int r = 0; r < reps; ++r) {
    s_pm[w][o] =
        edge_partial(beg, end - beg, o, s_nbr, vb, ui, bo, wcol, s_h[w]);
    __syncthreads();
    if (w == 0) {
      float acc = fmaxf(fmaxf(s_pm[0][o], s_pm[1][o]),
                        fmaxf(s_pm[2][o], s_pm[3][o]));
      raw_out[row * 64 + o] = acc;
      s_xs[o] = acc;
    }
    __syncthreads();
    {
      const float* Wb = W1n + 64 * 64;
      int kb = (w & 1) * 32;
      float a = (w == 0) ? b1n[o] : 0.f;
      if (w < 2) {
#pragma unroll
        for (int k = 0; k < 32; k++) {
          int kk = kb + k;
          a = fmaf(s_xs[kk], W1n[kk * 64 + o] - Wb[kk * 64 + o], a);
        }
      } else {
#pragma unroll
        for (int k = 0; k < 32; k++) {
          int kk = kb + k;
          a = fmaf(s_xs[kk], Wb[kk * 64 + o], a);
        }
      }
      s_pm[w][o] = a;
    }
    __syncthreads();
    if (w == 0) un[row * 64 + o] = s_pm[0][o] + s_pm[1][o];
    else if (w == 1) vn[row * 64 + o] = s_pm[2][o] + s_pm[3][o];
    __syncthreads();  // protect s_pm before next rep overwrites
  }
}

// PROBE: empty kernel, same grid shape -> pure launch/gap cost.
__global__ __launch_bounds__(256) void k_empty() {}

// K4: EdgeConv3 + residual(ec2_raw) + head MLP 64->128->3 (both relu).
__global__ __launch_bounds__(256) void k_edgeconv_final(
    const int* __restrict__ nbrCnt, const int* __restrict__ nbrG,
    const float* __restrict__ u, const float* __restrict__ v,
    const float* __restrict__ W2, const float* __restrict__ b2,
    const float* __restrict__ res,
    const float* __restrict__ Wh6, const float* __restrict__ bh6,
    const float* __restrict__ Wout, const float* __restrict__ bout,
    float* __restrict__ out) {
  __shared__ int s_nbr[MAXNBR];
  __shared__ float s_h[4][64 * 4];
  __shared__ float s_pm[4][64];
  __shared__ float s_xs[64];
  __shared__ float s_ph[2][128];
  __shared__ float s_op[2][3];
  int row = blockIdx.x;
  int tid = threadIdx.x;
  int w = tid >> 6, o = tid & 63;
  int cnt = __builtin_amdgcn_readfirstlane(nbrCnt[row]);
  if (tid < MAXNBR) s_nbr[tid] = (tid < cnt) ? nbrG[row * MAXNBR + tid] : 0;
  float rv = (w == 0) ? res[row * 64 + o] : 0.f;
  float wcol[64];
#pragma unroll
  for (int k = 0; k < 64; k++) wcol[k] = W2[k * 64 + o];
  float ui = u[row * 64 + o];
  float bo = b2[o];
  const float* vb = v + (size_t)(row >> 9) * (512 * 64);
  __syncthreads();
  int q = (cnt + 3) >> 2;
  int beg = w * q;
  if (beg > cnt) beg = cnt;
  int end = beg + q;
  if (end > cnt) end = cnt;
  s_pm[w][o] = edge_partial(beg, end - beg, o, s_nbr, vb, ui, bo, wcol, s_h[w]);
  __syncthreads();
  if (w == 0) {
    float acc = fmaxf(fmaxf(s_pm[0][o], s_pm[1][o]),
                      fmaxf(s_pm[2][o], s_pm[3][o]));
    s_xs[o] = acc + rv;
  }
  __syncthreads();
  // Head MLP 64->128, 4-way: output-half = w&1, k-half = w>>1.
  {
    int oc = (w & 1) * 64 + o;
    int kb = (w >> 1) * 32;
    float a = 0.f;
#pragma unroll
    for (int k = 0; k < 32; k++) {
      int kk = kb + k;
      a = fmaf(s_xs[kk], Wh6[kk * 128 + oc], a);
    }
    s_ph[w >> 1][oc] = a;
  }
  __syncthreads();
  // 128->3 via per-lane products + wave shfl reduction (waves 0,1).
  if (tid < 128) {
    float h6 = fmaxf(s_ph[0][tid] + s_ph[1][tid] + bh6[tid], 0.f);
    float p0 = h6 * Wout[tid * 3 + 0];
    float p1 = h6 * Wout[tid * 3 + 1];
    float p2 = h6 * Wout[tid * 3 + 2];
#pragma unroll
    for (int d = 32; d; d >>= 1) {
      p0 += __shfl_xor(p0, d);
      p1 += __shfl_xor(p1, d);
      p2 += __shfl_xor(p2, d);
    }
    if (o == 0) {
      s_op[w][0] = p0;
      s_op[w][1] = p1;
      s_op[w][2] = p2;
    }
  }
  __syncthreads();
  if (tid < 3)
    out[row * 3 + tid] = fmaxf(s_op[0][tid] + s_op[1][tid] + bout[tid], 0.f);
}

extern "C" void kernel_launch(void* const* d_in, const int* in_sizes, int n_in,
                              void* d_out, int out_size, void* d_ws,
                              size_t ws_size, hipStream_t stream) {
  const float* coords = (const float*)d_in[0];
  const float* A      = (const float*)d_in[1];
  const float* nf     = (const float*)d_in[2];
  const float* cs     = (const float*)d_in[3];
  const float* Wh1 = (const float*)d_in[4];
  const float* bh1 = (const float*)d_in[5];
  const float* Wh2 = (const float*)d_in[6];
  const float* bh2 = (const float*)d_in[7];
  const float* e1W1 = (const float*)d_in[8];
  const float* e1b1 = (const float*)d_in[9];
  const float* e1W2 = (const float*)d_in[10];
  const float* e1b2 = (const float*)d_in[11];
  const float* e2W1 = (const float*)d_in[12];
  const float* e2b1 = (const float*)d_in[13];
  const float* e2W2 = (const float*)d_in[14];
  const float* e2b2 = (const float*)d_in[15];
  const float* e3W1 = (const float*)d_in[16];
  const float* e3b1 = (const float*)d_in[17];
  const float* e3W2 = (const float*)d_in[18];
  const float* e3b2 = (const float*)d_in[19];
  const float* Wh6 = (const float*)d_in[20];
  const float* bh6 = (const float*)d_in[21];
  const float* Wout = (const float*)d_in[22];
  const float* bout = (const float*)d_in[23];

  float* ws = (float*)d_ws;
  float* u1  = ws + 0 * 65536;
  float* v1  = ws + 1 * 65536;
  float* e1o = ws + 2 * 65536;
  float* u2  = ws + 3 * 65536;
  float* v2  = ws + 4 * 65536;
  float* e2r = ws + 5 * 65536;
  float* u3  = ws + 6 * 65536;
  float* v3  = ws + 7 * 65536;
  int* wsI = (int*)(ws + 8 * 65536);
  int* nbrCnt = wsI;         // 1024 ints
  int* nbrG   = wsI + 1024;  // 1024*96 ints
  // Probe scratch (disjoint from pipeline buffers).
  float* pr_o = ws + 16 * 65536;
  float* pr_u = ws + 17 * 65536;
  float* pr_v = ws + 18 * 65536;
  float* out = (float*)d_out;

  k1_node_uv<<<dim3(1024), dim3(256), 0, stream>>>(
      coords, A, nf, cs, Wh1, bh1, Wh2, bh2, e1W1, e1b1, u1, v1, nbrCnt, nbrG);
  k_edgeconv_uv<<<dim3(1024), dim3(256), 0, stream>>>(
      nbrCnt, nbrG, u1, v1, e1W2, e1b2, nullptr, e1o, e2W1, e2b1, u2, v2);
  k_edgeconv_uv<<<dim3(1024), dim3(256), 0, stream>>>(
      nbrCnt, nbrG, u2, v2, e2W2, e2b2, e1o, e2r, e3W1, e3b1, u3, v3);
  k_edgeconv_final<<<dim3(1024), dim3(256), 0, stream>>>(
      nbrCnt, nbrG, u3, v3, e3W2, e3b2, e2r, Wh6, bh6, Wout, bout, out);
  // --- probes (after real pipeline; outputs to scratch) ---
  k2_probe<<<dim3(1024), dim3(256), 0, stream>>>(
      nbrCnt, nbrG, u1, v1, e1W2, e1b2, pr_o, e2W1, e2b1, pr_u, pr_v, 16);
  k_empty<<<dim3(1024), dim3(256), 0, stream>>>();
  k_empty<<<dim3(1024), dim3(256), 0, stream>>>();
  k_empty<<<dim3(1024), dim3(256), 0, stream>>>();
  k_empty<<<dim3(1024), dim3(256), 0, stream>>>();
}

// Round 6
// 140.386 us; speedup vs baseline: 4.2261x; 4.2261x over previous
//
#include <hip/hip_runtime.h>
#include <hip/hip_bf16.h>

// B=2, N=512. row = b*512 + i, rows 0..1023.
// R8: occupancy attack. R7 probe showed warm EdgeConv is stall-bound
// (VALUBusy 16%, bank-conflicts 0, HBM ~0) at VGPR=156 -> 3 waves/SIMD.
// Fix: W2 columns move from 64 VGPRs/lane (wcol[64]) into LDS (16 KB/block,
// staged once); inner loop reads w_lds[k*64+o] (2-way bank alias = free).
// __launch_bounds__(256,4) pins >=4 waves/SIMD so all 1024 blocks co-reside.
// Probes removed; pipeline structure = R5 (137.1 us).
//
// EdgeConv factorization: e@W1 = x_i@(W1_top - W1_bot) + x_j@W1_bot
//   u_i = x_i@(W1_top-W1_bot)+b1 ; v_j = x_j@W1_bot ; h1 = relu(u_i+v_j)
// Masked max over neighbors only (A>0) is exact: h2 = relu(..) >= 0 > -1e9.

#define NEGV -1e9f
#define MAXNBR 96

// Per-wave edge-max partial over edges [beg, beg+myc) of this row.
// Barrier-free: hbuf producer == consumer wave (DS ops in-order per wave), so
// the v-prefetch global loads stay in flight across groups.
// w_lds = W2 staged in LDS, [k][o] row-major (64x64).
__device__ __forceinline__ float edge_partial(
    int beg, int myc, int o, const int* nbr, const float* __restrict__ vb,
    float ui, float bo, const float* w_lds, float* hbuf) {
  float acc = NEGV;
  if (myc <= 0) return acc;
  float vl[4];
#pragma unroll
  for (int t = 0; t < 4; t++) {
    int e = t < myc ? t : myc - 1;
    vl[t] = vb[nbr[beg + e] * 64 + o];
  }
  for (int e0 = 0; e0 < myc; e0 += 4) {
    float4 hw;
    hw.x = fmaxf(ui + vl[0], 0.f);
    hw.y = fmaxf(ui + vl[1], 0.f);
    hw.z = fmaxf(ui + vl[2], 0.f);
    hw.w = fmaxf(ui + vl[3], 0.f);
    *(float4*)(hbuf + o * 4) = hw;
    if (e0 + 4 < myc) {
#pragma unroll
      for (int t = 0; t < 4; t++) {
        int e = e0 + 4 + t;
        if (e >= myc) e = myc - 1;
        vl[t] = vb[nbr[beg + e] * 64 + o];  // prefetch next group
      }
    }
    float s0 = bo, s1 = bo, s2 = bo, s3 = bo;
#pragma unroll
    for (int k = 0; k < 64; k++) {
      float4 hv = *(const float4*)(hbuf + k * 4);  // broadcast read
      float wv = w_lds[k * 64 + o];                // 2-way alias = free
      s0 = fmaf(hv.x, wv, s0);
      s1 = fmaf(hv.y, wv, s1);
      s2 = fmaf(hv.z, wv, s2);
      s3 = fmaf(hv.w, wv, s3);
    }
    acc = fmaxf(acc, fmaxf(s0, 0.f));
    if (e0 + 1 < myc) acc = fmaxf(acc, fmaxf(s1, 0.f));
    if (e0 + 2 < myc) acc = fmaxf(acc, fmaxf(s2, 0.f));
    if (e0 + 3 < myc) acc = fmaxf(acc, fmaxf(s3, 0.f));
  }
  return acc;
}

// K1: nbr-list build (wave1) + node MLP 3->64->64 (wave0) + 4-way u1/v1 GEMV.
__global__ __launch_bounds__(256) void k1_node_uv(
    const float* __restrict__ coords, const float* __restrict__ A,
    const float* __restrict__ nf, const float* __restrict__ cs,
    const float* __restrict__ Wh1, const float* __restrict__ bh1,
    const float* __restrict__ Wh2, const float* __restrict__ bh2,
    const float* __restrict__ W1, const float* __restrict__ b1,
    float* __restrict__ u, float* __restrict__ v,
    int* __restrict__ nbrCnt, int* __restrict__ nbrG) {
  int node = blockIdx.x;
  int tid = threadIdx.x;
  int w = tid >> 6, o = tid & 63;
  __shared__ float t[64];
  __shared__ float xs[128];
  __shared__ float pp[4][64];
  if (w == 1) {
    // Adjacency scan: two float4 loads cover the 512-wide row.
    const float* Arow = A + (size_t)node * 512;
    float4 a0 = *(const float4*)(Arow + o * 4);
    float4 a1 = *(const float4*)(Arow + 256 + o * 4);
    float av[8] = {a0.x, a0.y, a0.z, a0.w, a1.x, a1.y, a1.z, a1.w};
    int base = 0;
#pragma unroll
    for (int j = 0; j < 8; j++) {
      bool p = av[j] > 0.f;
      unsigned long long m = __ballot(p);
      if (p) {
        int pos = base + __builtin_popcountll(m & ((1ull << o) - 1ull));
        int col = (j < 4) ? (4 * o + j) : (256 + 4 * o + (j - 4));
        if (pos < MAXNBR) nbrG[node * MAXNBR + pos] = col;  // order-free (max)
      }
      base += __builtin_popcountll(m);
    }
    if (o == 0) nbrCnt[node] = base < MAXNBR ? base : MAXNBR;
  } else if (w == 0) {
    float c0 = coords[node * 3 + 0];
    float c1 = coords[node * 3 + 1];
    float c2 = coords[node * 3 + 2];
    float a = bh1[o];
    a = fmaf(c0, Wh1[o], a);
    a = fmaf(c1, Wh1[64 + o], a);
    a = fmaf(c2, Wh1[128 + o], a);
    t[o] = fmaxf(a, 0.f);  // same-wave producer/consumer: no barrier needed
    float a2 = bh2[o];
#pragma unroll
    for (int k = 0; k < 64; k++) a2 = fmaf(t[k], Wh2[k * 64 + o], a2);
    xs[o] = fmaxf(a2, 0.f);
    if (o < 63) xs[64 + o] = nf[node * 63 + o];
    if (o == 63) xs[127] = cs[node];
  }
  __syncthreads();
  // 4-way GEMV: w0/w1 = un k-halves of 128; w2/w3 = vn k-halves.
  {
    const float* WbG = W1 + 128 * 64;
    int kb = (w & 1) * 64;
    float a = (w == 0) ? b1[o] : 0.f;
    if (w < 2) {
#pragma unroll
      for (int k = 0; k < 64; k++) {
        int kk = kb + k;
        a = fmaf(xs[kk], W1[kk * 64 + o] - WbG[kk * 64 + o], a);
      }
    } else {
#pragma unroll
      for (int k = 0; k < 64; k++) {
        int kk = kb + k;
        a = fmaf(xs[kk], WbG[kk * 64 + o], a);
      }
    }
    pp[w][o] = a;
  }
  __syncthreads();
  if (w == 0) u[node * 64 + o] = pp[0][o] + pp[1][o];
  else if (w == 1) v[node * 64 + o] = pp[2][o] + pp[3][o];
}

// K2/K3: EdgeConv (+opt residual); writes raw out and u/v for next layer.
// Block = 256 threads (4 waves), one row per block, edges split 4-way,
// tail GEMVs split 4-way. W2 in LDS (not VGPRs) for occupancy.
__global__ __launch_bounds__(256, 4) void k_edgeconv_uv(
    const int* __restrict__ nbrCnt, const int* __restrict__ nbrG,
    const float* __restrict__ u, const float* __restrict__ v,
    const float* __restrict__ W2, const float* __restrict__ b2,
    const float* __restrict__ res,  // may be null
    float* __restrict__ raw_out,
    const float* __restrict__ W1n, const float* __restrict__ b1n,
    float* __restrict__ un, float* __restrict__ vn) {
  __shared__ int s_nbr[MAXNBR];
  __shared__ float s_h[4][64 * 4];
  __shared__ float s_pm[4][64];
  __shared__ float s_xs[64];
  __shared__ float s_w2[64 * 64];
  int row = blockIdx.x;
  int tid = threadIdx.x;
  int w = tid >> 6, o = tid & 63;
  int cnt = __builtin_amdgcn_readfirstlane(nbrCnt[row]);
  if (tid < MAXNBR) s_nbr[tid] = (tid < cnt) ? nbrG[row * MAXNBR + tid] : 0;
  // Stage W2 -> LDS: 4096 floats, 256 threads x 4 float4 (coalesced).
  {
    const float4* W24 = (const float4*)W2;
    float4* s_w24 = (float4*)s_w2;
#pragma unroll
    for (int t4 = 0; t4 < 4; t4++) s_w24[t4 * 256 + tid] = W24[t4 * 256 + tid];
  }
  float rv = (w == 0 && res) ? res[row * 64 + o] : 0.f;  // early, off-path
  float ui = u[row * 64 + o];
  float bo = b2[o];
  const float* vb = v + (size_t)(row >> 9) * (512 * 64);
  __syncthreads();
  int q = (cnt + 3) >> 2;
  int beg = w * q;
  if (beg > cnt) beg = cnt;
  int end = beg + q;
  if (end > cnt) end = cnt;
  s_pm[w][o] = edge_partial(beg, end - beg, o, s_nbr, vb, ui, bo, s_w2, s_h[w]);
  __syncthreads();
  if (w == 0) {
    float acc = fmaxf(fmaxf(s_pm[0][o], s_pm[1][o]),
                      fmaxf(s_pm[2][o], s_pm[3][o]));
    raw_out[row * 64 + o] = acc;
    s_xs[o] = acc + rv;
  }
  __syncthreads();
  // 4-way tail GEMV: w0/w1 = un k-halves of 64; w2/w3 = vn k-halves.
  {
    const float* Wb = W1n + 64 * 64;
    int kb = (w & 1) * 32;
    float a = (w == 0) ? b1n[o] : 0.f;
    if (w < 2) {
#pragma unroll
      for (int k = 0; k < 32; k++) {
        int kk = kb + k;
        a = fmaf(s_xs[kk], W1n[kk * 64 + o] - Wb[kk * 64 + o], a);
      }
    } else {
#pragma unroll
      for (int k = 0; k < 32; k++) {
        int kk = kb + k;
        a = fmaf(s_xs[kk], Wb[kk * 64 + o], a);
      }
    }
    s_pm[w][o] = a;  // reuse: edge partials consumed above (barrier-separated)
  }
  __syncthreads();
  if (w == 0) un[row * 64 + o] = s_pm[0][o] + s_pm[1][o];
  else if (w == 1) vn[row * 64 + o] = s_pm[2][o] + s_pm[3][o];
}

// K4: EdgeConv3 + residual(ec2_raw) + head MLP 64->128->3 (both relu).
__global__ __launch_bounds__(256, 4) void k_edgeconv_final(
    const int* __restrict__ nbrCnt, const int* __restrict__ nbrG,
    const float* __restrict__ u, const float* __restrict__ v,
    const float* __restrict__ W2, const float* __restrict__ b2,
    const float* __restrict__ res,
    const float* __restrict__ Wh6, const float* __restrict__ bh6,
    const float* __restrict__ Wout, const float* __restrict__ bout,
    float* __restrict__ out) {
  __shared__ int s_nbr[MAXNBR];
  __shared__ float s_h[4][64 * 4];
  __shared__ float s_pm[4][64];
  __shared__ float s_xs[64];
  __shared__ float s_w2[64 * 64];
  __shared__ float s_ph[2][128];
  __shared__ float s_op[2][3];
  int row = blockIdx.x;
  int tid = threadIdx.x;
  int w = tid >> 6, o = tid & 63;
  int cnt = __builtin_amdgcn_readfirstlane(nbrCnt[row]);
  if (tid < MAXNBR) s_nbr[tid] = (tid < cnt) ? nbrG[row * MAXNBR + tid] : 0;
  {
    const float4* W24 = (const float4*)W2;
    float4* s_w24 = (float4*)s_w2;
#pragma unroll
    for (int t4 = 0; t4 < 4; t4++) s_w24[t4 * 256 + tid] = W24[t4 * 256 + tid];
  }
  float rv = (w == 0) ? res[row * 64 + o] : 0.f;
  float ui = u[row * 64 + o];
  float bo = b2[o];
  const float* vb = v + (size_t)(row >> 9) * (512 * 64);
  __syncthreads();
  int q = (cnt + 3) >> 2;
  int beg = w * q;
  if (beg > cnt) beg = cnt;
  int end = beg + q;
  if (end > cnt) end = cnt;
  s_pm[w][o] = edge_partial(beg, end - beg, o, s_nbr, vb, ui, bo, s_w2, s_h[w]);
  __syncthreads();
  if (w == 0) {
    float acc = fmaxf(fmaxf(s_pm[0][o], s_pm[1][o]),
                      fmaxf(s_pm[2][o], s_pm[3][o]));
    s_xs[o] = acc + rv;
  }
  __syncthreads();
  // Head MLP 64->128, 4-way: output-half = w&1, k-half = w>>1.
  {
    int oc = (w & 1) * 64 + o;
    int kb = (w >> 1) * 32;
    float a = 0.f;
#pragma unroll
    for (int k = 0; k < 32; k++) {
      int kk = kb + k;
      a = fmaf(s_xs[kk], Wh6[kk * 128 + oc], a);
    }
    s_ph[w >> 1][oc] = a;
  }
  __syncthreads();
  // 128->3 via per-lane products + wave shfl reduction (waves 0,1).
  if (tid < 128) {
    float h6 = fmaxf(s_ph[0][tid] + s_ph[1][tid] + bh6[tid], 0.f);
    float p0 = h6 * Wout[tid * 3 + 0];
    float p1 = h6 * Wout[tid * 3 + 1];
    float p2 = h6 * Wout[tid * 3 + 2];
#pragma unroll
    for (int d = 32; d; d >>= 1) {
      p0 += __shfl_xor(p0, d);
      p1 += __shfl_xor(p1, d);
      p2 += __shfl_xor(p2, d);
    }
    if (o == 0) {
      s_op[w][0] = p0;
      s_op[w][1] = p1;
      s_op[w][2] = p2;
    }
  }
  __syncthreads();
  if (tid < 3)
    out[row * 3 + tid] = fmaxf(s_op[0][tid] + s_op[1][tid] + bout[tid], 0.f);
}

extern "C" void kernel_launch(void* const* d_in, const int* in_sizes, int n_in,
                              void* d_out, int out_size, void* d_ws,
                              size_t ws_size, hipStream_t stream) {
  const float* coords = (const float*)d_in[0];
  const float* A      = (const float*)d_in[1];
  const float* nf     = (const float*)d_in[2];
  const float* cs     = (const float*)d_in[3];
  const float* Wh1 = (const float*)d_in[4];
  const float* bh1 = (const float*)d_in[5];
  const float* Wh2 = (const float*)d_in[6];
  const float* bh2 = (const float*)d_in[7];
  const float* e1W1 = (const float*)d_in[8];
  const float* e1b1 = (const float*)d_in[9];
  const float* e1W2 = (const float*)d_in[10];
  const float* e1b2 = (const float*)d_in[11];
  const float* e2W1 = (const float*)d_in[12];
  const float* e2b1 = (const float*)d_in[13];
  const float* e2W2 = (const float*)d_in[14];
  const float* e2b2 = (const float*)d_in[15];
  const float* e3W1 = (const float*)d_in[16];
  const float* e3b1 = (const float*)d_in[17];
  const float* e3W2 = (const float*)d_in[18];
  const float* e3b2 = (const float*)d_in[19];
  const float* Wh6 = (const float*)d_in[20];
  const float* bh6 = (const float*)d_in[21];
  const float* Wout = (const float*)d_in[22];
  const float* bout = (const float*)d_in[23];

  float* ws = (float*)d_ws;
  float* u1  = ws + 0 * 65536;
  float* v1  = ws + 1 * 65536;
  float* e1o = ws + 2 * 65536;
  float* u2  = ws + 3 * 65536;
  float* v2  = ws + 4 * 65536;
  float* e2r = ws + 5 * 65536;
  float* u3  = ws + 6 * 65536;
  float* v3  = ws + 7 * 65536;
  int* wsI = (int*)(ws + 8 * 65536);
  int* nbrCnt = wsI;         // 1024 ints
  int* nbrG   = wsI + 1024;  // 1024*96 ints
  float* out = (float*)d_out;

  k1_node_uv<<<dim3(1024), dim3(256), 0, stream>>>(
      coords, A, nf, cs, Wh1, bh1, Wh2, bh2, e1W1, e1b1, u1, v1, nbrCnt, nbrG);
  k_edgeconv_uv<<<dim3(1024), dim3(256), 0, stream>>>(
      nbrCnt, nbrG, u1, v1, e1W2, e1b2, nullptr, e1o, e2W1, e2b1, u2, v2);
  k_edgeconv_uv<<<dim3(1024), dim3(256), 0, stream>>>(
      nbrCnt, nbrG, u2, v2, e2W2, e2b2, e1o, e2r, e3W1, e3b1, u3, v3);
  k_edgeconv_final<<<dim3(1024), dim3(256), 0, stream>>>(
      nbrCnt, nbrG, u3, v3, e3W2, e3b2, e2r, Wh6, bh6, Wout, bout, out);
}

// Round 7
// 136.915 us; speedup vs baseline: 4.3332x; 1.0254x over previous
//
#include <hip/hip_runtime.h>
#include <hip/hip_bf16.h>

// B=2, N=512. row = b*512 + i, rows 0..1023.
// R9 = REVERT to R5 (best verified: 137.1 µs). R8's W2->LDS move regressed
// (140.4): it added 64 ds_read_b32/group to the hot loop; occupancy was not
// the binding constraint (probe chain R4/R5: per-kernel cost is dominated by
// the kernel-boundary latency ramp — inter-kernel L2 invalidate + L3 refetch
// — not by warm issue work, DS throughput, or launch gaps).
// Structural floor: ~90 µs fixed harness fills/capture + 4 x ~11.6 µs.
//
// EdgeConv factorization: e@W1 = x_i@(W1_top - W1_bot) + x_j@W1_bot
//   u_i = x_i@(W1_top-W1_bot)+b1 ; v_j = x_j@W1_bot ; h1 = relu(u_i+v_j)
// Masked max over neighbors only (A>0) is exact: h2 = relu(..) >= 0 > -1e9.

#define NEGV -1e9f
#define MAXNBR 96

// Per-wave edge-max partial over edges [beg, beg+myc) of this row.
// Barrier-free: hbuf producer == consumer wave (DS ops in-order per wave), so
// the v-prefetch global loads stay in flight across groups.
__device__ __forceinline__ float edge_partial(
    int beg, int myc, int o, const int* nbr, const float* __restrict__ vb,
    float ui, float bo, const float* wcol, float* hbuf) {
  float acc = NEGV;
  if (myc <= 0) return acc;
  float vl[4];
#pragma unroll
  for (int t = 0; t < 4; t++) {
    int e = t < myc ? t : myc - 1;
    vl[t] = vb[nbr[beg + e] * 64 + o];
  }
  for (int e0 = 0; e0 < myc; e0 += 4) {
    float4 hw;
    hw.x = fmaxf(ui + vl[0], 0.f);
    hw.y = fmaxf(ui + vl[1], 0.f);
    hw.z = fmaxf(ui + vl[2], 0.f);
    hw.w = fmaxf(ui + vl[3], 0.f);
    *(float4*)(hbuf + o * 4) = hw;
    if (e0 + 4 < myc) {
#pragma unroll
      for (int t = 0; t < 4; t++) {
        int e = e0 + 4 + t;
        if (e >= myc) e = myc - 1;
        vl[t] = vb[nbr[beg + e] * 64 + o];  // prefetch next group
      }
    }
    float s0 = bo, s1 = bo, s2 = bo, s3 = bo;
#pragma unroll
    for (int k = 0; k < 64; k++) {
      float4 hv = *(const float4*)(hbuf + k * 4);  // broadcast read
      s0 = fmaf(hv.x, wcol[k], s0);
      s1 = fmaf(hv.y, wcol[k], s1);
      s2 = fmaf(hv.z, wcol[k], s2);
      s3 = fmaf(hv.w, wcol[k], s3);
    }
    acc = fmaxf(acc, fmaxf(s0, 0.f));
    if (e0 + 1 < myc) acc = fmaxf(acc, fmaxf(s1, 0.f));
    if (e0 + 2 < myc) acc = fmaxf(acc, fmaxf(s2, 0.f));
    if (e0 + 3 < myc) acc = fmaxf(acc, fmaxf(s3, 0.f));
  }
  return acc;
}

// K1: nbr-list build (wave1) + node MLP 3->64->64 (wave0) + 4-way u1/v1 GEMV.
__global__ __launch_bounds__(256) void k1_node_uv(
    const float* __restrict__ coords, const float* __restrict__ A,
    const float* __restrict__ nf, const float* __restrict__ cs,
    const float* __restrict__ Wh1, const float* __restrict__ bh1,
    const float* __restrict__ Wh2, const float* __restrict__ bh2,
    const float* __restrict__ W1, const float* __restrict__ b1,
    float* __restrict__ u, float* __restrict__ v,
    int* __restrict__ nbrCnt, int* __restrict__ nbrG) {
  int node = blockIdx.x;
  int tid = threadIdx.x;
  int w = tid >> 6, o = tid & 63;
  __shared__ float t[64];
  __shared__ float xs[128];
  __shared__ float pp[4][64];
  if (w == 1) {
    // Adjacency scan: two float4 loads cover the 512-wide row.
    const float* Arow = A + (size_t)node * 512;
    float4 a0 = *(const float4*)(Arow + o * 4);
    float4 a1 = *(const float4*)(Arow + 256 + o * 4);
    float av[8] = {a0.x, a0.y, a0.z, a0.w, a1.x, a1.y, a1.z, a1.w};
    int base = 0;
#pragma unroll
    for (int j = 0; j < 8; j++) {
      bool p = av[j] > 0.f;
      unsigned long long m = __ballot(p);
      if (p) {
        int pos = base + __builtin_popcountll(m & ((1ull << o) - 1ull));
        int col = (j < 4) ? (4 * o + j) : (256 + 4 * o + (j - 4));
        if (pos < MAXNBR) nbrG[node * MAXNBR + pos] = col;  // order-free (max)
      }
      base += __builtin_popcountll(m);
    }
    if (o == 0) nbrCnt[node] = base < MAXNBR ? base : MAXNBR;
  } else if (w == 0) {
    float c0 = coords[node * 3 + 0];
    float c1 = coords[node * 3 + 1];
    float c2 = coords[node * 3 + 2];
    float a = bh1[o];
    a = fmaf(c0, Wh1[o], a);
    a = fmaf(c1, Wh1[64 + o], a);
    a = fmaf(c2, Wh1[128 + o], a);
    t[o] = fmaxf(a, 0.f);  // same-wave producer/consumer: no barrier needed
    float a2 = bh2[o];
#pragma unroll
    for (int k = 0; k < 64; k++) a2 = fmaf(t[k], Wh2[k * 64 + o], a2);
    xs[o] = fmaxf(a2, 0.f);
    if (o < 63) xs[64 + o] = nf[node * 63 + o];
    if (o == 63) xs[127] = cs[node];
  }
  __syncthreads();
  // 4-way GEMV: w0/w1 = un k-halves of 128; w2/w3 = vn k-halves.
  {
    const float* WbG = W1 + 128 * 64;
    int kb = (w & 1) * 64;
    float a = (w == 0) ? b1[o] : 0.f;
    if (w < 2) {
#pragma unroll
      for (int k = 0; k < 64; k++) {
        int kk = kb + k;
        a = fmaf(xs[kk], W1[kk * 64 + o] - WbG[kk * 64 + o], a);
      }
    } else {
#pragma unroll
      for (int k = 0; k < 64; k++) {
        int kk = kb + k;
        a = fmaf(xs[kk], WbG[kk * 64 + o], a);
      }
    }
    pp[w][o] = a;
  }
  __syncthreads();
  if (w == 0) u[node * 64 + o] = pp[0][o] + pp[1][o];
  else if (w == 1) v[node * 64 + o] = pp[2][o] + pp[3][o];
}

// K2/K3: EdgeConv (+opt residual); writes raw out and u/v for next layer.
// Block = 256 threads (4 waves), one row per block, edges split 4-way,
// tail GEMVs split 4-way.
__global__ __launch_bounds__(256) void k_edgeconv_uv(
    const int* __restrict__ nbrCnt, const int* __restrict__ nbrG,
    const float* __restrict__ u, const float* __restrict__ v,
    const float* __restrict__ W2, const float* __restrict__ b2,
    const float* __restrict__ res,  // may be null
    float* __restrict__ raw_out,
    const float* __restrict__ W1n, const float* __restrict__ b1n,
    float* __restrict__ un, float* __restrict__ vn) {
  __shared__ int s_nbr[MAXNBR];
  __shared__ float s_h[4][64 * 4];
  __shared__ float s_pm[4][64];
  __shared__ float s_xs[64];
  int row = blockIdx.x;
  int tid = threadIdx.x;
  int w = tid >> 6, o = tid & 63;
  int cnt = __builtin_amdgcn_readfirstlane(nbrCnt[row]);
  if (tid < MAXNBR) s_nbr[tid] = (tid < cnt) ? nbrG[row * MAXNBR + tid] : 0;
  float rv = (w == 0 && res) ? res[row * 64 + o] : 0.f;  // early, off-path
  float wcol[64];
#pragma unroll
  for (int k = 0; k < 64; k++) wcol[k] = W2[k * 64 + o];
  float ui = u[row * 64 + o];
  float bo = b2[o];
  const float* vb = v + (size_t)(row >> 9) * (512 * 64);
  __syncthreads();
  int q = (cnt + 3) >> 2;
  int beg = w * q;
  if (beg > cnt) beg = cnt;
  int end = beg + q;
  if (end > cnt) end = cnt;
  s_pm[w][o] = edge_partial(beg, end - beg, o, s_nbr, vb, ui, bo, wcol, s_h[w]);
  __syncthreads();
  if (w == 0) {
    float acc = fmaxf(fmaxf(s_pm[0][o], s_pm[1][o]),
                      fmaxf(s_pm[2][o], s_pm[3][o]));
    raw_out[row * 64 + o] = acc;
    s_xs[o] = acc + rv;
  }
  __syncthreads();
  // 4-way tail GEMV: w0/w1 = un k-halves of 64; w2/w3 = vn k-halves.
  {
    const float* Wb = W1n + 64 * 64;
    int kb = (w & 1) * 32;
    float a = (w == 0) ? b1n[o] : 0.f;
    if (w < 2) {
#pragma unroll
      for (int k = 0; k < 32; k++) {
        int kk = kb + k;
        a = fmaf(s_xs[kk], W1n[kk * 64 + o] - Wb[kk * 64 + o], a);
      }
    } else {
#pragma unroll
      for (int k = 0; k < 32; k++) {
        int kk = kb + k;
        a = fmaf(s_xs[kk], Wb[kk * 64 + o], a);
      }
    }
    s_pm[w][o] = a;  // reuse: edge partials consumed above (barrier-separated)
  }
  __syncthreads();
  if (w == 0) un[row * 64 + o] = s_pm[0][o] + s_pm[1][o];
  else if (w == 1) vn[row * 64 + o] = s_pm[2][o] + s_pm[3][o];
}

// K4: EdgeConv3 + residual(ec2_raw) + head MLP 64->128->3 (both relu).
__global__ __launch_bounds__(256) void k_edgeconv_final(
    const int* __restrict__ nbrCnt, const int* __restrict__ nbrG,
    const float* __restrict__ u, const float* __restrict__ v,
    const float* __restrict__ W2, const float* __restrict__ b2,
    const float* __restrict__ res,
    const float* __restrict__ Wh6, const float* __restrict__ bh6,
    const float* __restrict__ Wout, const float* __restrict__ bout,
    float* __restrict__ out) {
  __shared__ int s_nbr[MAXNBR];
  __shared__ float s_h[4][64 * 4];
  __shared__ float s_pm[4][64];
  __shared__ float s_xs[64];
  __shared__ float s_ph[2][128];
  __shared__ float s_op[2][3];
  int row = blockIdx.x;
  int tid = threadIdx.x;
  int w = tid >> 6, o = tid & 63;
  int cnt = __builtin_amdgcn_readfirstlane(nbrCnt[row]);
  if (tid < MAXNBR) s_nbr[tid] = (tid < cnt) ? nbrG[row * MAXNBR + tid] : 0;
  float rv = (w == 0) ? res[row * 64 + o] : 0.f;
  float wcol[64];
#pragma unroll
  for (int k = 0; k < 64; k++) wcol[k] = W2[k * 64 + o];
  float ui = u[row * 64 + o];
  float bo = b2[o];
  const float* vb = v + (size_t)(row >> 9) * (512 * 64);
  __syncthreads();
  int q = (cnt + 3) >> 2;
  int beg = w * q;
  if (beg > cnt) beg = cnt;
  int end = beg + q;
  if (end > cnt) end = cnt;
  s_pm[w][o] = edge_partial(beg, end - beg, o, s_nbr, vb, ui, bo, wcol, s_h[w]);
  __syncthreads();
  if (w == 0) {
    float acc = fmaxf(fmaxf(s_pm[0][o], s_pm[1][o]),
                      fmaxf(s_pm[2][o], s_pm[3][o]));
    s_xs[o] = acc + rv;
  }
  __syncthreads();
  // Head MLP 64->128, 4-way: output-half = w&1, k-half = w>>1.
  {
    int oc = (w & 1) * 64 + o;
    int kb = (w >> 1) * 32;
    float a = 0.f;
#pragma unroll
    for (int k = 0; k < 32; k++) {
      int kk = kb + k;
      a = fmaf(s_xs[kk], Wh6[kk * 128 + oc], a);
    }
    s_ph[w >> 1][oc] = a;
  }
  __syncthreads();
  // 128->3 via per-lane products + wave shfl reduction (waves 0,1).
  if (tid < 128) {
    float h6 = fmaxf(s_ph[0][tid] + s_ph[1][tid] + bh6[tid], 0.f);
    float p0 = h6 * Wout[tid * 3 + 0];
    float p1 = h6 * Wout[tid * 3 + 1];
    float p2 = h6 * Wout[tid * 3 + 2];
#pragma unroll
    for (int d = 32; d; d >>= 1) {
      p0 += __shfl_xor(p0, d);
      p1 += __shfl_xor(p1, d);
      p2 += __shfl_xor(p2, d);
    }
    if (o == 0) {
      s_op[w][0] = p0;
      s_op[w][1] = p1;
      s_op[w][2] = p2;
    }
  }
  __syncthreads();
  if (tid < 3)
    out[row * 3 + tid] = fmaxf(s_op[0][tid] + s_op[1][tid] + bout[tid], 0.f);
}

extern "C" void kernel_launch(void* const* d_in, const int* in_sizes, int n_in,
                              void* d_out, int out_size, void* d_ws,
                              size_t ws_size, hipStream_t stream) {
  const float* coords = (const float*)d_in[0];
  const float* A      = (const float*)d_in[1];
  const float* nf     = (const float*)d_in[2];
  const float* cs     = (const float*)d_in[3];
  const float* Wh1 = (const float*)d_in[4];
  const float* bh1 = (const float*)d_in[5];
  const float* Wh2 = (const float*)d_in[6];
  const float* bh2 = (const float*)d_in[7];
  const float* e1W1 = (const float*)d_in[8];
  const float* e1b1 = (const float*)d_in[9];
  const float* e1W2 = (const float*)d_in[10];
  const float* e1b2 = (const float*)d_in[11];
  const float* e2W1 = (const float*)d_in[12];
  const float* e2b1 = (const float*)d_in[13];
  const float* e2W2 = (const float*)d_in[14];
  const float* e2b2 = (const float*)d_in[15];
  const float* e3W1 = (const float*)d_in[16];
  const float* e3b1 = (const float*)d_in[17];
  const float* e3W2 = (const float*)d_in[18];
  const float* e3b2 = (const float*)d_in[19];
  const float* Wh6 = (const float*)d_in[20];
  const float* bh6 = (const float*)d_in[21];
  const float* Wout = (const float*)d_in[22];
  const float* bout = (const float*)d_in[23];

  float* ws = (float*)d_ws;
  float* u1  = ws + 0 * 65536;
  float* v1  = ws + 1 * 65536;
  float* e1o = ws + 2 * 65536;
  float* u2  = ws + 3 * 65536;
  float* v2  = ws + 4 * 65536;
  float* e2r = ws + 5 * 65536;
  float* u3  = ws + 6 * 65536;
  float* v3  = ws + 7 * 65536;
  int* wsI = (int*)(ws + 8 * 65536);
  int* nbrCnt = wsI;         // 1024 ints
  int* nbrG   = wsI + 1024;  // 1024*96 ints
  float* out = (float*)d_out;

  k1_node_uv<<<dim3(1024), dim3(256), 0, stream>>>(
      coords, A, nf, cs, Wh1, bh1, Wh2, bh2, e1W1, e1b1, u1, v1, nbrCnt, nbrG);
  k_edgeconv_uv<<<dim3(1024), dim3(256), 0, stream>>>(
      nbrCnt, nbrG, u1, v1, e1W2, e1b2, nullptr, e1o, e2W1, e2b1, u2, v2);
  k_edgeconv_uv<<<dim3(1024), dim3(256), 0, stream>>>(
      nbrCnt, nbrG, u2, v2, e2W2, e2b2, e1o, e2r, e3W1, e3b1, u3, v3);
  k_edgeconv_final<<<dim3(1024), dim3(256), 0, stream>>>(
      nbrCnt, nbrG, u3, v3, e3W2, e3b2, e2r, Wh6, bh6, Wout, bout, out);
}